// Round 4
// baseline (1060.815 us; speedup 1.0000x reference)
//
#include <hip/hip_runtime.h>
#include <hip/hip_cooperative_groups.h>

namespace cg = cooperative_groups;

#define DIM 128
#define HID 32

// bf16 helpers (RNE), values finite
static __device__ __forceinline__ unsigned short f2bf(float f) {
    unsigned int u = __float_as_uint(f);
    u += 0x7fffu + ((u >> 16) & 1u);
    return (unsigned short)(u >> 16);
}
static __device__ __forceinline__ float bf2f(unsigned short s) {
    return __uint_as_float((unsigned int)s << 16);
}

__global__ __launch_bounds__(256, 6) void mega_kernel(
    const float* __restrict__ x, const int* __restrict__ ei,
    const float* __restrict__ W, const float* __restrict__ b_gcn,
    const float* __restrict__ w1, const float* __restrict__ b1,
    const float* __restrict__ w2, const float* __restrict__ b2,
    const float* __restrict__ w3, const float* __restrict__ b3,
    float* __restrict__ out,
    unsigned short* __restrict__ xwb, int* __restrict__ degi,
    float* __restrict__ dinv, int* __restrict__ offs, int* __restrict__ cur,
    int* __restrict__ bsum, int2* __restrict__ csr, int n, int E)
{
    cg::grid_group grid = cg::this_grid();
    __shared__ float smem[16 * DIM];          // 8 KB, reused by every phase
    const int t    = threadIdx.x;
    const int tid  = blockIdx.x * 256 + t;
    const int nthr = gridDim.x * 256;
    const int* col = ei + E;

    // ---------- P0: zero degree histogram ----------
    for (int i = tid; i < n; i += nthr) degi[i] = 0;
    grid.sync();

    // ---------- P1: gemm tiles (xw bf16) + degree count, one task list ----------
    const int ngemm = (n + 15) / 16;
    const int ndeg  = (E + 1023) / 1024;
    for (int task = blockIdx.x; task < ngemm + ndeg; task += gridDim.x) {
        if (task < ngemm) {
            int row0 = task * 16;
            const float4* xg = (const float4*)(x + (size_t)row0 * DIM);
#pragma unroll
            for (int i = 0; i < 2; ++i) {
                int f = t + i * 256;
                int rl = f >> 5;
                float4 v = make_float4(0.f, 0.f, 0.f, 0.f);
                if (row0 + rl < n) v = xg[f];
                ((float4*)smem)[f] = v;
            }
            __syncthreads();
            int j = t & 31, rr = t >> 5;
            float a0x = 0.f, a0y = 0.f, a0z = 0.f, a0w = 0.f;
            float a1x = 0.f, a1y = 0.f, a1z = 0.f, a1w = 0.f;
            for (int k = 0; k < DIM; k += 4) {
                float4 xa = *(const float4*)&smem[rr * DIM + k];
                float4 xb = *(const float4*)&smem[(rr + 8) * DIM + k];
#pragma unroll
                for (int i = 0; i < 4; ++i) {
                    float4 wv = *(const float4*)&W[(k + i) * DIM + 4 * j];
                    float xai = (i == 0) ? xa.x : (i == 1) ? xa.y : (i == 2) ? xa.z : xa.w;
                    float xbi = (i == 0) ? xb.x : (i == 1) ? xb.y : (i == 2) ? xb.z : xb.w;
                    a0x += xai * wv.x; a0y += xai * wv.y; a0z += xai * wv.z; a0w += xai * wv.w;
                    a1x += xbi * wv.x; a1y += xbi * wv.y; a1z += xbi * wv.z; a1w += xbi * wv.w;
                }
            }
            int rowA = row0 + rr, rowB = row0 + rr + 8;
            if (rowA < n) {
                ushort4 o; o.x = f2bf(a0x); o.y = f2bf(a0y); o.z = f2bf(a0z); o.w = f2bf(a0w);
                ((ushort4*)(xwb + (size_t)rowA * DIM))[j] = o;
            }
            if (rowB < n) {
                ushort4 o; o.x = f2bf(a1x); o.y = f2bf(a1y); o.z = f2bf(a1z); o.w = f2bf(a1w);
                ((ushort4*)(xwb + (size_t)rowB * DIM))[j] = o;
            }
            __syncthreads();   // smem reused next task
        } else {
            int base = (task - ngemm) * 1024 + t * 4;
            if (base + 3 < E) {
                int4 v = *(const int4*)&col[base];
                atomicAdd(&degi[v.x], 1); atomicAdd(&degi[v.y], 1);
                atomicAdd(&degi[v.z], 1); atomicAdd(&degi[v.w], 1);
            } else {
                for (int e = base; e < E; ++e) atomicAdd(&degi[col[e]], 1);
            }
        }
    }
    grid.sync();

    // ---------- P2: per-1024-chunk exclusive scan of degi -> offs, chunk sums ----------
    const int nchunk = (n + 1023) / 1024;
    int* wsum = (int*)smem;
    for (int c = blockIdx.x; c < nchunk; c += gridDim.x) {
        int i0 = c * 1024 + t * 4;
        int va = 0, vb = 0, vc = 0, vd = 0;
        if (i0 + 3 < n) {
            int4 q = *(const int4*)&degi[i0];
            va = q.x; vb = q.y; vc = q.z; vd = q.w;
        } else {
            if (i0     < n) va = degi[i0];
            if (i0 + 1 < n) vb = degi[i0 + 1];
            if (i0 + 2 < n) vc = degi[i0 + 2];
        }
        int s1 = va + vb, s2 = s1 + vc, tot = s2 + vd;
        int lane = t & 63;
        int inc = tot;
#pragma unroll
        for (int off = 1; off < 64; off <<= 1) {
            int u = __shfl_up(inc, off);
            if (lane >= off) inc += u;
        }
        int texcl = inc - tot;
        if (lane == 63) wsum[t >> 6] = inc;
        __syncthreads();
        if (t == 0) {
            int acc = 0;
#pragma unroll
            for (int w = 0; w < 4; ++w) { int u = wsum[w]; wsum[4 + w] = acc; acc += u; }
        }
        __syncthreads();
        int excl = wsum[4 + (t >> 6)] + texcl;
        if (i0 + 3 < n) {
            int4 o; o.x = excl; o.y = excl + va; o.z = excl + s1; o.w = excl + s2;
            *(int4*)&offs[i0] = o;
        } else {
            if (i0     < n) offs[i0]     = excl;
            if (i0 + 1 < n) offs[i0 + 1] = excl + va;
            if (i0 + 2 < n) offs[i0 + 2] = excl + s1;
        }
        if (t == 255) bsum[c] = excl + tot;
        __syncthreads();
    }
    grid.sync();

    // ---------- P3: exclusive scan of chunk sums (nchunk <= 64), one wave ----------
    if (blockIdx.x == 0 && t < 64) {
        int v = (t < nchunk) ? bsum[t] : 0;
        int orig = v;
#pragma unroll
        for (int off = 1; off < 64; off <<= 1) {
            int u = __shfl_up(v, off);
            if (t >= off) v += u;
        }
        if (t < nchunk) bsum[t] = v - orig;
    }
    grid.sync();

    // ---------- P4: add chunk prefix; init cursors; dinv ----------
    for (int i = tid; i < n; i += nthr) {
        int o = offs[i] + bsum[i >> 10];
        offs[i] = o;
        cur[i]  = o;
        dinv[i] = rsqrtf((float)degi[i] + 1.0f);   // self-loop included
    }
    grid.sync();

    // ---------- P5: fill CSR buckets int2{src, bits(dinv[src])} ----------
    for (int e = tid; e < E; e += nthr) {
        int r = ei[e], c = col[e];
        int p = atomicAdd(&cur[c], 1);
        csr[p] = make_int2(r, __float_as_int(dinv[r]));
    }
    grid.sync();

    // ---------- P6: gather + self-loop + bias/relu/residual + MLP ----------
    float* hs  = smem;             // 8*132 floats
    float* t1s = smem + 8 * 132;   // 8*40 floats
    int r = t >> 5, j = t & 31;
    const int ngrp = (n + 7) / 8;
    for (int g = blockIdx.x; g < ngrp; g += gridDim.x) {
        int node = g * 8 + r;
        if (node < n) {
            int beg = offs[node];
            int end = beg + degi[node];
            float ax = 0.f, ay = 0.f, az = 0.f, aw = 0.f;
            int q = beg;
            for (; q + 2 <= end; q += 2) {
                int2 e0 = csr[q];
                int2 e1 = csr[q + 1];
                ushort4 v0 = ((const ushort4*)(xwb + (size_t)e0.x * DIM))[j];
                ushort4 v1 = ((const ushort4*)(xwb + (size_t)e1.x * DIM))[j];
                float w0 = __int_as_float(e0.y);
                float w1_ = __int_as_float(e1.y);
                ax += w0 * bf2f(v0.x) + w1_ * bf2f(v1.x);
                ay += w0 * bf2f(v0.y) + w1_ * bf2f(v1.y);
                az += w0 * bf2f(v0.z) + w1_ * bf2f(v1.z);
                aw += w0 * bf2f(v0.w) + w1_ * bf2f(v1.w);
            }
            if (q < end) {
                int2 e0 = csr[q];
                ushort4 v0 = ((const ushort4*)(xwb + (size_t)e0.x * DIM))[j];
                float w0 = __int_as_float(e0.y);
                ax += w0 * bf2f(v0.x); ay += w0 * bf2f(v0.y);
                az += w0 * bf2f(v0.z); aw += w0 * bf2f(v0.w);
            }
            float di = dinv[node];
            float sdi = di * di;
            ushort4 a = ((const ushort4*)(xwb + (size_t)node * DIM))[j];
            float4 xv = ((const float4*)(x + (size_t)node * DIM))[j];
            float4 bg = ((const float4*)b_gcn)[j];
            float* h = &hs[r * 132 + 4 * j];
            h[0] = fmaxf(di * ax + sdi * bf2f(a.x) + bg.x, 0.f) + xv.x;
            h[1] = fmaxf(di * ay + sdi * bf2f(a.y) + bg.y, 0.f) + xv.y;
            h[2] = fmaxf(di * az + sdi * bf2f(a.z) + bg.z, 0.f) + xv.z;
            h[3] = fmaxf(di * aw + sdi * bf2f(a.w) + bg.w, 0.f) + xv.w;
        }
        __syncthreads();
        // layer 1: 128 -> 32
        float acc = b1[j];
        for (int k = 0; k < DIM; k += 4) {
            float4 hv = *(const float4*)&hs[r * 132 + k];
            acc += hv.x * w1[(k + 0) * HID + j];
            acc += hv.y * w1[(k + 1) * HID + j];
            acc += hv.z * w1[(k + 2) * HID + j];
            acc += hv.w * w1[(k + 3) * HID + j];
        }
        t1s[r * 40 + j] = fmaxf(acc, 0.0f);
        __syncthreads();
        // layer 2: 32 -> 32
        acc = b2[j];
        for (int k = 0; k < HID; k += 4) {
            float4 tv = *(const float4*)&t1s[r * 40 + k];
            acc += tv.x * w2[(k + 0) * HID + j];
            acc += tv.y * w2[(k + 1) * HID + j];
            acc += tv.z * w2[(k + 2) * HID + j];
            acc += tv.w * w2[(k + 3) * HID + j];
        }
        // layer 3: 32 -> 1, shuffle-reduce
        float v = fmaxf(acc, 0.0f) * w3[j];
#pragma unroll
        for (int off = 16; off > 0; off >>= 1) v += __shfl_down(v, off, 32);
        if (j == 0 && node < n) out[node] = v + b3[0];
        // no trailing barrier needed: next-iter hs writes are fenced by this
        // iter's post-layer1 barrier semantics (hs reads all complete by then)
        __syncthreads();
    }
}

extern "C" void kernel_launch(void* const* d_in, const int* in_sizes, int n_in,
                              void* d_out, int out_size, void* d_ws, size_t ws_size,
                              hipStream_t stream) {
    const float* x     = (const float*)d_in[0];
    const int*   ei    = (const int*)d_in[1];
    const float* W_gcn = (const float*)d_in[2];
    const float* b_gcn = (const float*)d_in[3];
    const float* w1    = (const float*)d_in[4];
    const float* b1    = (const float*)d_in[5];
    const float* w2    = (const float*)d_in[6];
    const float* b2    = (const float*)d_in[7];
    const float* w3    = (const float*)d_in[8];
    const float* b3    = (const float*)d_in[9];
    float* out = (float*)d_out;

    int n = in_sizes[0] / DIM;     // 50000
    int E = in_sizes[1] / 2;       // 600000

    // workspace layout
    char* ws = (char*)d_ws;
    unsigned short* xwb = (unsigned short*)ws;              // 12.8 MB bf16
    char* p = ws + (size_t)n * DIM * sizeof(unsigned short);
    int*   degi = (int*)p;           p += (size_t)n * sizeof(int);
    float* dinv = (float*)p;         p += (size_t)n * sizeof(float);
    int*   offs = (int*)p;           p += (size_t)n * sizeof(int);
    int*   cur  = (int*)p;           p += (size_t)n * sizeof(int);
    int*   bsum = (int*)p;           p += 256 * sizeof(int);
    p = (char*)(((size_t)p + 15) & ~(size_t)15);
    int2*  csr  = (int2*)p;                                  // 4.8 MB

    // grid size: co-resident blocks (cooperative launch requirement)
    int maxb = 0;
    hipOccupancyMaxActiveBlocksPerMultiprocessor(&maxb,
        reinterpret_cast<const void*>(mega_kernel), 256, 0);
    int ncu = 0;
    hipDeviceGetAttribute(&ncu, hipDeviceAttributeMultiprocessorCount, 0);
    if (ncu <= 0) ncu = 256;
    if (maxb <= 0) maxb = 6;            // guaranteed by __launch_bounds__(256,6)
    if (maxb > 8) maxb = 8;             // waves/CU cap at 256 threads/block
    int nblk = maxb * ncu;

    void* args[] = {
        (void*)&x, (void*)&ei, (void*)&W_gcn, (void*)&b_gcn,
        (void*)&w1, (void*)&b1, (void*)&w2, (void*)&b2, (void*)&w3, (void*)&b3,
        (void*)&out, (void*)&xwb, (void*)&degi, (void*)&dinv, (void*)&offs,
        (void*)&cur, (void*)&bsum, (void*)&csr, (void*)&n, (void*)&E
    };
    hipLaunchCooperativeKernel(reinterpret_cast<void*>(mega_kernel),
                               dim3(nblk), dim3(256), args, 0, stream);
}

// Round 5
// 805.650 us; speedup vs baseline: 1.3167x; 1.3167x over previous
//
#include <hip/hip_runtime.h>

#define DIM 128
#define HID 32

// bf16 helpers (RNE), values finite
static __device__ __forceinline__ unsigned short f2bf(float f) {
    unsigned int u = __float_as_uint(f);
    u += 0x7fffu + ((u >> 16) & 1u);
    return (unsigned short)(u >> 16);
}
static __device__ __forceinline__ float bf2f(unsigned short s) {
    return __uint_as_float((unsigned int)s << 16);
}

// ---------------- deg count: in-degree over targets (col), int4 ----------------
__global__ __launch_bounds__(256) void deg_count_kernel(const int* __restrict__ col,
                                                        int* __restrict__ degi, int E) {
    int base = (blockIdx.x * 256 + threadIdx.x) * 4;
    if (base + 3 < E) {
        int4 v = *(const int4*)&col[base];
        atomicAdd(&degi[v.x], 1); atomicAdd(&degi[v.y], 1);
        atomicAdd(&degi[v.z], 1); atomicAdd(&degi[v.w], 1);
    } else {
        for (int e = base; e < E; ++e) atomicAdd(&degi[col[e]], 1);
    }
}

// ---------------- single-dispatch scan: offs/cur = exclusive_scan(degi) ----------------
// block c: redundant prefix reduction over degi[0 .. c*1024), then scan own chunk.
__global__ __launch_bounds__(256) void scan_kernel(const int* __restrict__ degi,
                                                   int* __restrict__ offs,
                                                   int* __restrict__ cur, int n) {
    __shared__ int sh[16];
    const int c = blockIdx.x, t = threadIdx.x;
    const int lim = c << 10;
    // prefix = sum of all earlier chunks (lim is a multiple of 1024, <= n)
    int s = 0;
    for (int i = t * 4; i < lim; i += 1024) {
        int4 q = *(const int4*)&degi[i];
        s += q.x + q.y + q.z + q.w;
    }
#pragma unroll
    for (int off = 32; off > 0; off >>= 1) s += __shfl_down(s, off);
    if ((t & 63) == 0) sh[t >> 6] = s;
    __syncthreads();
    if (t == 0) sh[4] = sh[0] + sh[1] + sh[2] + sh[3];
    __syncthreads();
    const int pre = sh[4];

    // scan own 1024-chunk (4 elements/thread)
    int i0 = lim + t * 4;
    int va = 0, vb = 0, vc = 0, vd = 0;
    if (i0 + 3 < n) {
        int4 q = *(const int4*)&degi[i0];
        va = q.x; vb = q.y; vc = q.z; vd = q.w;
    } else {
        if (i0     < n) va = degi[i0];
        if (i0 + 1 < n) vb = degi[i0 + 1];
        if (i0 + 2 < n) vc = degi[i0 + 2];
    }
    int s1 = va + vb, s2 = s1 + vc, tot = s2 + vd;
    int lane = t & 63;
    int inc = tot;
#pragma unroll
    for (int off = 1; off < 64; off <<= 1) {
        int u = __shfl_up(inc, off);
        if (lane >= off) inc += u;
    }
    int texcl = inc - tot;
    if (lane == 63) sh[8 + (t >> 6)] = inc;
    __syncthreads();
    if (t == 0) {
        int a = 0;
#pragma unroll
        for (int w = 0; w < 4; ++w) { int u = sh[8 + w]; sh[12 + w] = a; a += u; }
    }
    __syncthreads();
    int excl = pre + sh[12 + (t >> 6)] + texcl;
    if (i0 + 3 < n) {
        int4 o; o.x = excl; o.y = excl + va; o.z = excl + s1; o.w = excl + s2;
        *(int4*)&offs[i0] = o;
        *(int4*)&cur[i0]  = o;
    } else {
        if (i0     < n) { offs[i0]     = excl;      cur[i0]     = excl; }
        if (i0 + 1 < n) { offs[i0 + 1] = excl + va; cur[i0 + 1] = excl + va; }
        if (i0 + 2 < n) { offs[i0 + 2] = excl + s1; cur[i0 + 2] = excl + s1; }
    }
}

// ---------------- fill CSR buckets: int2{src, bits(dinv[src])} grouped by target ----------------
__global__ __launch_bounds__(256) void fill_kernel(const int* __restrict__ ei,
                                                   const int* __restrict__ degi,
                                                   int* __restrict__ cur,
                                                   int2* __restrict__ csr, int E) {
    int e = blockIdx.x * 256 + threadIdx.x;
    if (e >= E) return;
    int r = ei[e];          // source
    int c = ei[E + e];      // target
    int p = atomicAdd(&cur[c], 1);
    float w = rsqrtf((float)degi[r] + 1.0f);   // dinv[src], self-loop included
    csr[p] = make_int2(r, __float_as_int(w));
}

// ---------------- xw(bf16) = x @ W  ([N,128] @ [128,128]) ----------------
// 32 rows/block, 256 threads; thread = 4 rows x 4 cols register tile.
__global__ __launch_bounds__(256) void gemm_xw_kernel(const float* __restrict__ x,
                                                      const float* __restrict__ W,
                                                      unsigned short* __restrict__ xwb, int n) {
    __shared__ float xs[32 * DIM];     // 16 KB
    int t = threadIdx.x;
    int row0 = blockIdx.x * 32;
    const float4* xg = (const float4*)(x + (size_t)row0 * DIM);
#pragma unroll
    for (int i = 0; i < 4; ++i) {
        int f = t + i * 256;
        int rl = f >> 5;                       // float4-index -> local row
        float4 v = make_float4(0.f, 0.f, 0.f, 0.f);
        if (row0 + rl < n) v = xg[f];
        ((float4*)xs)[f] = v;
    }
    __syncthreads();
    int j = t & 31;                            // col group (4 cols)
    int rr = t >> 5;                           // local rows rr, rr+8, rr+16, rr+24
    float acc[4][4] = {};
    for (int k = 0; k < DIM; k += 4) {
        float4 xv[4];
        xv[0] = *(const float4*)&xs[(rr +  0) * DIM + k];
        xv[1] = *(const float4*)&xs[(rr +  8) * DIM + k];
        xv[2] = *(const float4*)&xs[(rr + 16) * DIM + k];
        xv[3] = *(const float4*)&xs[(rr + 24) * DIM + k];
#pragma unroll
        for (int i = 0; i < 4; ++i) {
            float4 wv = *(const float4*)&W[(k + i) * DIM + 4 * j];
#pragma unroll
            for (int rg = 0; rg < 4; ++rg) {
                float xi = (i == 0) ? xv[rg].x : (i == 1) ? xv[rg].y
                         : (i == 2) ? xv[rg].z : xv[rg].w;
                acc[rg][0] += xi * wv.x; acc[rg][1] += xi * wv.y;
                acc[rg][2] += xi * wv.z; acc[rg][3] += xi * wv.w;
            }
        }
    }
#pragma unroll
    for (int rg = 0; rg < 4; ++rg) {
        int row = row0 + rr + 8 * rg;
        if (row < n) {
            ushort4 o;
            o.x = f2bf(acc[rg][0]); o.y = f2bf(acc[rg][1]);
            o.z = f2bf(acc[rg][2]); o.w = f2bf(acc[rg][3]);
            ((ushort4*)(xwb + (size_t)row * DIM))[j] = o;
        }
    }
}

// ---------------- fused: CSR gather + self-loop + bias/relu/residual + MLP ----------------
// 8 nodes/block; 32 threads/node; thread j owns channels 4j..4j+3.
__global__ __launch_bounds__(256) void gather_tail_kernel(
    const unsigned short* __restrict__ xwb, const float* __restrict__ x,
    const int* __restrict__ offs, const int* __restrict__ degi,
    const int2* __restrict__ csr, const float* __restrict__ b_gcn,
    const float* __restrict__ w1, const float* __restrict__ b1,
    const float* __restrict__ w2, const float* __restrict__ b2,
    const float* __restrict__ w3, const float* __restrict__ b3,
    float* __restrict__ out, int n) {
    __shared__ float hs[8 * 132];   // 16B-aligned rows, conflict-free
    __shared__ float t1s[8 * 40];
    int t = threadIdx.x;
    int r = t >> 5, j = t & 31;
    int node = blockIdx.x * 8 + r;

    if (node < n) {
        int beg = offs[node];
        int d = degi[node];
        float ax = 0.f, ay = 0.f, az = 0.f, aw = 0.f;
        for (int c0 = 0; c0 < d; c0 += 32) {
            int2 e = make_int2(0, 0);
            if (c0 + j < d) e = csr[beg + c0 + j];
            int m = min(32, d - c0);
            for (int i = 0; i < m; ++i) {
                int src = __shfl(e.x, i, 32);
                float w = __int_as_float(__shfl(e.y, i, 32));
                ushort4 v = ((const ushort4*)(xwb + (size_t)src * DIM))[j];
                ax += w * bf2f(v.x); ay += w * bf2f(v.y);
                az += w * bf2f(v.z); aw += w * bf2f(v.w);
            }
        }
        float di = rsqrtf((float)d + 1.0f);
        float sdi = di * di;
        ushort4 a = ((const ushort4*)(xwb + (size_t)node * DIM))[j];
        float4 xv = ((const float4*)(x + (size_t)node * DIM))[j];
        float4 bg = ((const float4*)b_gcn)[j];
        float* h = &hs[r * 132 + 4 * j];
        h[0] = fmaxf(di * ax + sdi * bf2f(a.x) + bg.x, 0.f) + xv.x;
        h[1] = fmaxf(di * ay + sdi * bf2f(a.y) + bg.y, 0.f) + xv.y;
        h[2] = fmaxf(di * az + sdi * bf2f(a.z) + bg.z, 0.f) + xv.z;
        h[3] = fmaxf(di * aw + sdi * bf2f(a.w) + bg.w, 0.f) + xv.w;
    }
    __syncthreads();
    // layer 1: 128 -> 32
    float acc = b1[j];
    for (int k = 0; k < DIM; k += 4) {
        float4 hv = *(const float4*)&hs[r * 132 + k];
        acc += hv.x * w1[(k + 0) * HID + j];
        acc += hv.y * w1[(k + 1) * HID + j];
        acc += hv.z * w1[(k + 2) * HID + j];
        acc += hv.w * w1[(k + 3) * HID + j];
    }
    t1s[r * 40 + j] = fmaxf(acc, 0.0f);
    __syncthreads();
    // layer 2: 32 -> 32
    acc = b2[j];
    for (int k = 0; k < HID; k += 4) {
        float4 tv = *(const float4*)&t1s[r * 40 + k];
        acc += tv.x * w2[(k + 0) * HID + j];
        acc += tv.y * w2[(k + 1) * HID + j];
        acc += tv.z * w2[(k + 2) * HID + j];
        acc += tv.w * w2[(k + 3) * HID + j];
    }
    // layer 3: 32 -> 1, shuffle-reduce across the 32 threads of this node
    float v = fmaxf(acc, 0.0f) * w3[j];
#pragma unroll
    for (int off = 16; off > 0; off >>= 1) v += __shfl_down(v, off, 32);
    if (j == 0 && node < n) out[node] = v + b3[0];
}

extern "C" void kernel_launch(void* const* d_in, const int* in_sizes, int n_in,
                              void* d_out, int out_size, void* d_ws, size_t ws_size,
                              hipStream_t stream) {
    const float* x     = (const float*)d_in[0];
    const int*   ei    = (const int*)d_in[1];
    const float* W_gcn = (const float*)d_in[2];
    const float* b_gcn = (const float*)d_in[3];
    const float* w1    = (const float*)d_in[4];
    const float* b1    = (const float*)d_in[5];
    const float* w2    = (const float*)d_in[6];
    const float* b2    = (const float*)d_in[7];
    const float* w3    = (const float*)d_in[8];
    const float* b3    = (const float*)d_in[9];
    float* out = (float*)d_out;

    const int n = in_sizes[0] / DIM;     // 50000
    const int E = in_sizes[1] / 2;       // 600000

    // workspace layout
    char* ws = (char*)d_ws;
    unsigned short* xwb = (unsigned short*)ws;              // 12.8 MB bf16
    char* p = ws + (size_t)n * DIM * sizeof(unsigned short);
    int*   degi = (int*)p;           p += (size_t)n * sizeof(int);
    int*   offs = (int*)p;           p += (size_t)n * sizeof(int);
    int*   cur  = (int*)p;           p += (size_t)n * sizeof(int);
    p = (char*)(((size_t)p + 15) & ~(size_t)15);
    int2*  csr  = (int2*)p;                                  // 4.8 MB

    const int nchunk = (n + 1023) / 1024;   // 49

    hipMemsetAsync(degi, 0, (size_t)n * sizeof(int), stream);
    deg_count_kernel<<<(E + 1023) / 1024, 256, 0, stream>>>(ei + E, degi, E);
    scan_kernel<<<nchunk, 256, 0, stream>>>(degi, offs, cur, n);
    fill_kernel<<<(E + 255) / 256, 256, 0, stream>>>(ei, degi, cur, csr, E);
    gemm_xw_kernel<<<(n + 31) / 32, 256, 0, stream>>>(x, W_gcn, xwb, n);
    gather_tail_kernel<<<(n + 7) / 8, 256, 0, stream>>>(xwb, x, offs, degi, csr,
                                                        b_gcn, w1, b1, w2, b2,
                                                        w3, b3, out, n);
}

// Round 6
// 263.128 us; speedup vs baseline: 4.0316x; 3.0618x over previous
//
#include <hip/hip_runtime.h>

#define DIM 128
#define HID 32

// bf16 helpers (RNE), values finite
static __device__ __forceinline__ unsigned short f2bf(float f) {
    unsigned int u = __float_as_uint(f);
    u += 0x7fffu + ((u >> 16) & 1u);
    return (unsigned short)(u >> 16);
}
static __device__ __forceinline__ float bf2f(unsigned short s) {
    return __uint_as_float((unsigned int)s << 16);
}

// ---------------- deg count: in-degree over targets (col), int4 ----------------
__global__ __launch_bounds__(256) void deg_count_kernel(const int* __restrict__ col,
                                                        int* __restrict__ degi, int E) {
    int base = (blockIdx.x * 256 + threadIdx.x) * 4;
    if (base + 3 < E) {
        int4 v = *(const int4*)&col[base];
        atomicAdd(&degi[v.x], 1); atomicAdd(&degi[v.y], 1);
        atomicAdd(&degi[v.z], 1); atomicAdd(&degi[v.w], 1);
    } else {
        for (int e = base; e < E; ++e) atomicAdd(&degi[col[e]], 1);
    }
}

// ---------------- single-dispatch scan: offs/cur = exclusive_scan(degi) ----------------
// block c: redundant prefix reduction over degi[0 .. c*1024), then scan own chunk.
__global__ __launch_bounds__(256) void scan_kernel(const int* __restrict__ degi,
                                                   int* __restrict__ offs,
                                                   int* __restrict__ cur, int n) {
    __shared__ int sh[16];
    const int c = blockIdx.x, t = threadIdx.x;
    const int lim = c << 10;
    // prefix = sum of all earlier chunks (lim is a multiple of 1024, <= n)
    int s = 0;
    for (int i = t * 4; i < lim; i += 1024) {
        int4 q = *(const int4*)&degi[i];
        s += q.x + q.y + q.z + q.w;
    }
#pragma unroll
    for (int off = 32; off > 0; off >>= 1) s += __shfl_down(s, off);
    if ((t & 63) == 0) sh[t >> 6] = s;
    __syncthreads();
    if (t == 0) sh[4] = sh[0] + sh[1] + sh[2] + sh[3];
    __syncthreads();
    const int pre = sh[4];

    // scan own 1024-chunk (4 elements/thread)
    int i0 = lim + t * 4;
    int va = 0, vb = 0, vc = 0, vd = 0;
    if (i0 + 3 < n) {
        int4 q = *(const int4*)&degi[i0];
        va = q.x; vb = q.y; vc = q.z; vd = q.w;
    } else {
        if (i0     < n) va = degi[i0];
        if (i0 + 1 < n) vb = degi[i0 + 1];
        if (i0 + 2 < n) vc = degi[i0 + 2];
    }
    int s1 = va + vb, s2 = s1 + vc, tot = s2 + vd;
    int lane = t & 63;
    int inc = tot;
#pragma unroll
    for (int off = 1; off < 64; off <<= 1) {
        int u = __shfl_up(inc, off);
        if (lane >= off) inc += u;
    }
    int texcl = inc - tot;
    if (lane == 63) sh[8 + (t >> 6)] = inc;
    __syncthreads();
    if (t == 0) {
        int a = 0;
#pragma unroll
        for (int w = 0; w < 4; ++w) { int u = sh[8 + w]; sh[12 + w] = a; a += u; }
    }
    __syncthreads();
    int excl = pre + sh[12 + (t >> 6)] + texcl;
    if (i0 + 3 < n) {
        int4 o; o.x = excl; o.y = excl + va; o.z = excl + s1; o.w = excl + s2;
        *(int4*)&offs[i0] = o;
        *(int4*)&cur[i0]  = o;
    } else {
        if (i0     < n) { offs[i0]     = excl;      cur[i0]     = excl; }
        if (i0 + 1 < n) { offs[i0 + 1] = excl + va; cur[i0 + 1] = excl + va; }
        if (i0 + 2 < n) { offs[i0 + 2] = excl + s1; cur[i0 + 2] = excl + s1; }
    }
}

// ---------------- fill CSR buckets: int2{src, bits(dinv[src])} grouped by target ----------------
__global__ __launch_bounds__(256) void fill_kernel(const int* __restrict__ ei,
                                                   const int* __restrict__ degi,
                                                   int* __restrict__ cur,
                                                   int2* __restrict__ csr, int E) {
    int e = blockIdx.x * 256 + threadIdx.x;
    if (e >= E) return;
    int r = ei[e];          // source
    int c = ei[E + e];      // target
    int p = atomicAdd(&cur[c], 1);
    float w = rsqrtf((float)degi[r] + 1.0f);   // dinv[src], self-loop included
    csr[p] = make_int2(r, __float_as_int(w));
}

// ---------------- xw(bf16) = x @ W  ([N,128] @ [128,128]) ----------------
// 16 rows/block, 256 threads; thread = 2 rows x 4 cols register tile. (R3-proven, no spill)
__global__ __launch_bounds__(256) void gemm_xw_kernel(const float* __restrict__ x,
                                                      const float* __restrict__ W,
                                                      unsigned short* __restrict__ xwb, int n) {
    __shared__ float xs[16 * DIM];
    int t = threadIdx.x;
    int row0 = blockIdx.x * 16;
    const float4* xg = (const float4*)(x + (size_t)row0 * DIM);
#pragma unroll
    for (int i = 0; i < 2; ++i) {
        int f = t + i * 256;
        int rl = f >> 5;                       // float4 index -> local row
        float4 v = make_float4(0.f, 0.f, 0.f, 0.f);
        if (row0 + rl < n) v = xg[f];
        ((float4*)xs)[f] = v;
    }
    __syncthreads();
    int j = t & 31;                            // col group (4 cols)
    int rr = t >> 5;                           // local rows rr and rr+8
    float a0x = 0.f, a0y = 0.f, a0z = 0.f, a0w = 0.f;
    float a1x = 0.f, a1y = 0.f, a1z = 0.f, a1w = 0.f;
    for (int k = 0; k < DIM; k += 4) {
        float4 xa = *(const float4*)&xs[rr * DIM + k];
        float4 xb = *(const float4*)&xs[(rr + 8) * DIM + k];
#pragma unroll
        for (int i = 0; i < 4; ++i) {
            float4 wv = *(const float4*)&W[(k + i) * DIM + 4 * j];
            float xai = (i == 0) ? xa.x : (i == 1) ? xa.y : (i == 2) ? xa.z : xa.w;
            float xbi = (i == 0) ? xb.x : (i == 1) ? xb.y : (i == 2) ? xb.z : xb.w;
            a0x += xai * wv.x; a0y += xai * wv.y; a0z += xai * wv.z; a0w += xai * wv.w;
            a1x += xbi * wv.x; a1y += xbi * wv.y; a1z += xbi * wv.z; a1w += xbi * wv.w;
        }
    }
    int rowA = row0 + rr, rowB = row0 + rr + 8;
    if (rowA < n) {
        ushort4 o; o.x = f2bf(a0x); o.y = f2bf(a0y); o.z = f2bf(a0z); o.w = f2bf(a0w);
        ((ushort4*)(xwb + (size_t)rowA * DIM))[j] = o;
    }
    if (rowB < n) {
        ushort4 o; o.x = f2bf(a1x); o.y = f2bf(a1y); o.z = f2bf(a1z); o.w = f2bf(a1w);
        ((ushort4*)(xwb + (size_t)rowB * DIM))[j] = o;
    }
}

// ---------------- fused: CSR gather + self-loop + bias/relu/residual + MLP ----------------
// 8 nodes/block; 32 threads/node; thread j owns channels 4j..4j+3.
__global__ __launch_bounds__(256) void gather_tail_kernel(
    const unsigned short* __restrict__ xwb, const float* __restrict__ x,
    const int* __restrict__ offs, const int* __restrict__ degi,
    const int2* __restrict__ csr, const float* __restrict__ b_gcn,
    const float* __restrict__ w1, const float* __restrict__ b1,
    const float* __restrict__ w2, const float* __restrict__ b2,
    const float* __restrict__ w3, const float* __restrict__ b3,
    float* __restrict__ out, int n) {
    __shared__ float hs[8 * 132];   // 16B-aligned rows, conflict-free
    __shared__ float t1s[8 * 40];
    int t = threadIdx.x;
    int r = t >> 5, j = t & 31;
    int node = blockIdx.x * 8 + r;

    if (node < n) {
        int beg = offs[node];
        int d = degi[node];
        float ax = 0.f, ay = 0.f, az = 0.f, aw = 0.f;
        for (int c0 = 0; c0 < d; c0 += 32) {
            int2 e = make_int2(0, 0);
            if (c0 + j < d) e = csr[beg + c0 + j];
            int m = min(32, d - c0);
            for (int i = 0; i < m; ++i) {
                int src = __shfl(e.x, i, 32);
                float w = __int_as_float(__shfl(e.y, i, 32));
                ushort4 v = ((const ushort4*)(xwb + (size_t)src * DIM))[j];
                ax += w * bf2f(v.x); ay += w * bf2f(v.y);
                az += w * bf2f(v.z); aw += w * bf2f(v.w);
            }
        }
        float di = rsqrtf((float)d + 1.0f);
        float sdi = di * di;
        ushort4 a = ((const ushort4*)(xwb + (size_t)node * DIM))[j];
        float4 xv = ((const float4*)(x + (size_t)node * DIM))[j];
        float4 bg = ((const float4*)b_gcn)[j];
        float* h = &hs[r * 132 + 4 * j];
        h[0] = fmaxf(di * ax + sdi * bf2f(a.x) + bg.x, 0.f) + xv.x;
        h[1] = fmaxf(di * ay + sdi * bf2f(a.y) + bg.y, 0.f) + xv.y;
        h[2] = fmaxf(di * az + sdi * bf2f(a.z) + bg.z, 0.f) + xv.z;
        h[3] = fmaxf(di * aw + sdi * bf2f(a.w) + bg.w, 0.f) + xv.w;
    }
    __syncthreads();
    // layer 1: 128 -> 32
    float acc = b1[j];
    for (int k = 0; k < DIM; k += 4) {
        float4 hv = *(const float4*)&hs[r * 132 + k];
        acc += hv.x * w1[(k + 0) * HID + j];
        acc += hv.y * w1[(k + 1) * HID + j];
        acc += hv.z * w1[(k + 2) * HID + j];
        acc += hv.w * w1[(k + 3) * HID + j];
    }
    t1s[r * 40 + j] = fmaxf(acc, 0.0f);
    __syncthreads();
    // layer 2: 32 -> 32
    acc = b2[j];
    for (int k = 0; k < HID; k += 4) {
        float4 tv = *(const float4*)&t1s[r * 40 + k];
        acc += tv.x * w2[(k + 0) * HID + j];
        acc += tv.y * w2[(k + 1) * HID + j];
        acc += tv.z * w2[(k + 2) * HID + j];
        acc += tv.w * w2[(k + 3) * HID + j];
    }
    // layer 3: 32 -> 1, shuffle-reduce across the 32 threads of this node
    float v = fmaxf(acc, 0.0f) * w3[j];
#pragma unroll
    for (int off = 16; off > 0; off >>= 1) v += __shfl_down(v, off, 32);
    if (j == 0 && node < n) out[node] = v + b3[0];
}

extern "C" void kernel_launch(void* const* d_in, const int* in_sizes, int n_in,
                              void* d_out, int out_size, void* d_ws, size_t ws_size,
                              hipStream_t stream) {
    const float* x     = (const float*)d_in[0];
    const int*   ei    = (const int*)d_in[1];
    const float* W_gcn = (const float*)d_in[2];
    const float* b_gcn = (const float*)d_in[3];
    const float* w1    = (const float*)d_in[4];
    const float* b1    = (const float*)d_in[5];
    const float* w2    = (const float*)d_in[6];
    const float* b2    = (const float*)d_in[7];
    const float* w3    = (const float*)d_in[8];
    const float* b3    = (const float*)d_in[9];
    float* out = (float*)d_out;

    const int n = in_sizes[0] / DIM;     // 50000
    const int E = in_sizes[1] / 2;       // 600000

    // workspace layout
    char* ws = (char*)d_ws;
    unsigned short* xwb = (unsigned short*)ws;              // 12.8 MB bf16
    char* p = ws + (size_t)n * DIM * sizeof(unsigned short);
    int*   degi = (int*)p;           p += (size_t)n * sizeof(int);
    int*   offs = (int*)p;           p += (size_t)n * sizeof(int);
    int*   cur  = (int*)p;           p += (size_t)n * sizeof(int);
    p = (char*)(((size_t)p + 15) & ~(size_t)15);
    int2*  csr  = (int2*)p;                                  // 4.8 MB

    const int nchunk = (n + 1023) / 1024;   // 49

    hipMemsetAsync(degi, 0, (size_t)n * sizeof(int), stream);
    deg_count_kernel<<<(E + 1023) / 1024, 256, 0, stream>>>(ei + E, degi, E);
    scan_kernel<<<nchunk, 256, 0, stream>>>(degi, offs, cur, n);
    fill_kernel<<<(E + 255) / 256, 256, 0, stream>>>(ei, degi, cur, csr, E);
    gemm_xw_kernel<<<(n + 15) / 16, 256, 0, stream>>>(x, W_gcn, xwb, n);
    gather_tail_kernel<<<(n + 7) / 8, 256, 0, stream>>>(xwb, x, offs, degi, csr,
                                                        b_gcn, w1, b1, w2, b2,
                                                        w3, b3, out, n);
}

// Round 7
// 243.047 us; speedup vs baseline: 4.3647x; 1.0826x over previous
//
#include <hip/hip_runtime.h>

#define DIM 128
#define HID 32

// bf16 helpers (RNE), values finite
static __device__ __forceinline__ unsigned short f2bf(float f) {
    unsigned int u = __float_as_uint(f);
    u += 0x7fffu + ((u >> 16) & 1u);
    return (unsigned short)(u >> 16);
}
static __device__ __forceinline__ float bf2f(unsigned short s) {
    return __uint_as_float((unsigned int)s << 16);
}

// ---------------- K1: task list = gemm tiles (xw bf16) + degree-count chunks ----------------
// gemm: 16 rows/block, thread = 2 rows x 4 cols (R3-proven, no spill).
__global__ __launch_bounds__(256) void gemm_deg_kernel(const float* __restrict__ x,
                                                       const float* __restrict__ W,
                                                       unsigned short* __restrict__ xwb,
                                                       const int* __restrict__ col,
                                                       int* __restrict__ degi,
                                                       int n, int E, int ngemm) {
    __shared__ float xs[16 * DIM];
    int t = threadIdx.x;
    if ((int)blockIdx.x < ngemm) {
        int row0 = blockIdx.x * 16;
        const float4* xg = (const float4*)(x + (size_t)row0 * DIM);
#pragma unroll
        for (int i = 0; i < 2; ++i) {
            int f = t + i * 256;
            int rl = f >> 5;
            float4 v = make_float4(0.f, 0.f, 0.f, 0.f);
            if (row0 + rl < n) v = xg[f];
            ((float4*)xs)[f] = v;
        }
        __syncthreads();
        int j = t & 31;
        int rr = t >> 5;
        float a0x = 0.f, a0y = 0.f, a0z = 0.f, a0w = 0.f;
        float a1x = 0.f, a1y = 0.f, a1z = 0.f, a1w = 0.f;
        for (int k = 0; k < DIM; k += 4) {
            float4 xa = *(const float4*)&xs[rr * DIM + k];
            float4 xb = *(const float4*)&xs[(rr + 8) * DIM + k];
#pragma unroll
            for (int i = 0; i < 4; ++i) {
                float4 wv = *(const float4*)&W[(k + i) * DIM + 4 * j];
                float xai = (i == 0) ? xa.x : (i == 1) ? xa.y : (i == 2) ? xa.z : xa.w;
                float xbi = (i == 0) ? xb.x : (i == 1) ? xb.y : (i == 2) ? xb.z : xb.w;
                a0x += xai * wv.x; a0y += xai * wv.y; a0z += xai * wv.z; a0w += xai * wv.w;
                a1x += xbi * wv.x; a1y += xbi * wv.y; a1z += xbi * wv.z; a1w += xbi * wv.w;
            }
        }
        int rowA = row0 + rr, rowB = row0 + rr + 8;
        if (rowA < n) {
            ushort4 o; o.x = f2bf(a0x); o.y = f2bf(a0y); o.z = f2bf(a0z); o.w = f2bf(a0w);
            ((ushort4*)(xwb + (size_t)rowA * DIM))[j] = o;
        }
        if (rowB < n) {
            ushort4 o; o.x = f2bf(a1x); o.y = f2bf(a1y); o.z = f2bf(a1z); o.w = f2bf(a1w);
            ((ushort4*)(xwb + (size_t)rowB * DIM))[j] = o;
        }
    } else {
        int base = ((blockIdx.x - ngemm) * 256 + t) * 4;
        if (base + 3 < E) {
            int4 v = *(const int4*)&col[base];
            atomicAdd(&degi[v.x], 1); atomicAdd(&degi[v.y], 1);
            atomicAdd(&degi[v.z], 1); atomicAdd(&degi[v.w], 1);
        } else {
            for (int e = base; e < E; ++e) atomicAdd(&degi[col[e]], 1);
        }
    }
}

// ---------------- single-dispatch scan: offs/cur = exclusive_scan(degi) ----------------
__global__ __launch_bounds__(256) void scan_kernel(const int* __restrict__ degi,
                                                   int* __restrict__ offs,
                                                   int* __restrict__ cur, int n) {
    __shared__ int sh[16];
    const int c = blockIdx.x, t = threadIdx.x;
    const int lim = c << 10;
    int s = 0;
    for (int i = t * 4; i < lim; i += 1024) {
        int4 q = *(const int4*)&degi[i];
        s += q.x + q.y + q.z + q.w;
    }
#pragma unroll
    for (int off = 32; off > 0; off >>= 1) s += __shfl_down(s, off);
    if ((t & 63) == 0) sh[t >> 6] = s;
    __syncthreads();
    if (t == 0) sh[4] = sh[0] + sh[1] + sh[2] + sh[3];
    __syncthreads();
    const int pre = sh[4];

    int i0 = lim + t * 4;
    int va = 0, vb = 0, vc = 0, vd = 0;
    if (i0 + 3 < n) {
        int4 q = *(const int4*)&degi[i0];
        va = q.x; vb = q.y; vc = q.z; vd = q.w;
    } else {
        if (i0     < n) va = degi[i0];
        if (i0 + 1 < n) vb = degi[i0 + 1];
        if (i0 + 2 < n) vc = degi[i0 + 2];
    }
    int s1 = va + vb, s2 = s1 + vc, tot = s2 + vd;
    int lane = t & 63;
    int inc = tot;
#pragma unroll
    for (int off = 1; off < 64; off <<= 1) {
        int u = __shfl_up(inc, off);
        if (lane >= off) inc += u;
    }
    int texcl = inc - tot;
    if (lane == 63) sh[8 + (t >> 6)] = inc;
    __syncthreads();
    if (t == 0) {
        int a = 0;
#pragma unroll
        for (int w = 0; w < 4; ++w) { int u = sh[8 + w]; sh[12 + w] = a; a += u; }
    }
    __syncthreads();
    int excl = pre + sh[12 + (t >> 6)] + texcl;
    if (i0 + 3 < n) {
        int4 o; o.x = excl; o.y = excl + va; o.z = excl + s1; o.w = excl + s2;
        *(int4*)&offs[i0] = o;
        *(int4*)&cur[i0]  = o;
    } else {
        if (i0     < n) { offs[i0]     = excl;      cur[i0]     = excl; }
        if (i0 + 1 < n) { offs[i0 + 1] = excl + va; cur[i0 + 1] = excl + va; }
        if (i0 + 2 < n) { offs[i0 + 2] = excl + s1; cur[i0 + 2] = excl + s1; }
    }
}

// ---------------- fill CSR buckets, 4 edges/thread ----------------
__global__ __launch_bounds__(256) void fill_kernel(const int* __restrict__ ei,
                                                   const int* __restrict__ degi,
                                                   int* __restrict__ cur,
                                                   int2* __restrict__ csr, int E) {
    const int* col = ei + E;
    int base = (blockIdx.x * 256 + threadIdx.x) * 4;
    if (base + 3 < E) {
        int4 r4 = *(const int4*)&ei[base];
        int4 c4 = *(const int4*)&col[base];
        int p0 = atomicAdd(&cur[c4.x], 1);
        int p1 = atomicAdd(&cur[c4.y], 1);
        int p2 = atomicAdd(&cur[c4.z], 1);
        int p3 = atomicAdd(&cur[c4.w], 1);
        csr[p0] = make_int2(r4.x, __float_as_int(rsqrtf((float)degi[r4.x] + 1.0f)));
        csr[p1] = make_int2(r4.y, __float_as_int(rsqrtf((float)degi[r4.y] + 1.0f)));
        csr[p2] = make_int2(r4.z, __float_as_int(rsqrtf((float)degi[r4.z] + 1.0f)));
        csr[p3] = make_int2(r4.w, __float_as_int(rsqrtf((float)degi[r4.w] + 1.0f)));
    } else {
        for (int e = base; e < E; ++e) {
            int r = ei[e], c = col[e];
            int p = atomicAdd(&cur[c], 1);
            csr[p] = make_int2(r, __float_as_int(rsqrtf((float)degi[r] + 1.0f)));
        }
    }
}

// ---------------- fused: CSR gather + self-loop + bias/relu/residual + MLP ----------------
// 8 nodes/block; 32 threads/node; thread j owns channels 4j..4j+3.
// Edge loop unrolled 4x: 4 independent xw-row loads in flight.
__global__ __launch_bounds__(256) void gather_tail_kernel(
    const unsigned short* __restrict__ xwb, const float* __restrict__ x,
    const int* __restrict__ offs, const int* __restrict__ degi,
    const int2* __restrict__ csr, const float* __restrict__ b_gcn,
    const float* __restrict__ w1, const float* __restrict__ b1,
    const float* __restrict__ w2, const float* __restrict__ b2,
    const float* __restrict__ w3, const float* __restrict__ b3,
    float* __restrict__ out, int n) {
    __shared__ float hs[8 * 132];
    __shared__ float t1s[8 * 40];
    int t = threadIdx.x;
    int r = t >> 5, j = t & 31;
    int node = blockIdx.x * 8 + r;

    if (node < n) {
        int beg = offs[node];
        int d = degi[node];
        float ax = 0.f, ay = 0.f, az = 0.f, aw = 0.f;
        for (int c0 = 0; c0 < d; c0 += 32) {
            int2 e = make_int2(0, 0);
            if (c0 + j < d) e = csr[beg + c0 + j];
            int m = min(32, d - c0);
            int i = 0;
            for (; i + 4 <= m; i += 4) {
                int s0 = __shfl(e.x, i,     32);
                int s1 = __shfl(e.x, i + 1, 32);
                int s2 = __shfl(e.x, i + 2, 32);
                int s3 = __shfl(e.x, i + 3, 32);
                float w0 = __int_as_float(__shfl(e.y, i,     32));
                float w1_ = __int_as_float(__shfl(e.y, i + 1, 32));
                float w2_ = __int_as_float(__shfl(e.y, i + 2, 32));
                float w3_ = __int_as_float(__shfl(e.y, i + 3, 32));
                ushort4 v0 = ((const ushort4*)(xwb + (size_t)s0 * DIM))[j];
                ushort4 v1 = ((const ushort4*)(xwb + (size_t)s1 * DIM))[j];
                ushort4 v2 = ((const ushort4*)(xwb + (size_t)s2 * DIM))[j];
                ushort4 v3 = ((const ushort4*)(xwb + (size_t)s3 * DIM))[j];
                ax += w0 * bf2f(v0.x) + w1_ * bf2f(v1.x) + w2_ * bf2f(v2.x) + w3_ * bf2f(v3.x);
                ay += w0 * bf2f(v0.y) + w1_ * bf2f(v1.y) + w2_ * bf2f(v2.y) + w3_ * bf2f(v3.y);
                az += w0 * bf2f(v0.z) + w1_ * bf2f(v1.z) + w2_ * bf2f(v2.z) + w3_ * bf2f(v3.z);
                aw += w0 * bf2f(v0.w) + w1_ * bf2f(v1.w) + w2_ * bf2f(v2.w) + w3_ * bf2f(v3.w);
            }
            for (; i < m; ++i) {
                int src = __shfl(e.x, i, 32);
                float w = __int_as_float(__shfl(e.y, i, 32));
                ushort4 v = ((const ushort4*)(xwb + (size_t)src * DIM))[j];
                ax += w * bf2f(v.x); ay += w * bf2f(v.y);
                az += w * bf2f(v.z); aw += w * bf2f(v.w);
            }
        }
        float di = rsqrtf((float)d + 1.0f);
        float sdi = di * di;
        ushort4 a = ((const ushort4*)(xwb + (size_t)node * DIM))[j];
        float4 xv = ((const float4*)(x + (size_t)node * DIM))[j];
        float4 bg = ((const float4*)b_gcn)[j];
        float* h = &hs[r * 132 + 4 * j];
        h[0] = fmaxf(di * ax + sdi * bf2f(a.x) + bg.x, 0.f) + xv.x;
        h[1] = fmaxf(di * ay + sdi * bf2f(a.y) + bg.y, 0.f) + xv.y;
        h[2] = fmaxf(di * az + sdi * bf2f(a.z) + bg.z, 0.f) + xv.z;
        h[3] = fmaxf(di * aw + sdi * bf2f(a.w) + bg.w, 0.f) + xv.w;
    }
    __syncthreads();
    float acc = b1[j];
    for (int k = 0; k < DIM; k += 4) {
        float4 hv = *(const float4*)&hs[r * 132 + k];
        acc += hv.x * w1[(k + 0) * HID + j];
        acc += hv.y * w1[(k + 1) * HID + j];
        acc += hv.z * w1[(k + 2) * HID + j];
        acc += hv.w * w1[(k + 3) * HID + j];
    }
    t1s[r * 40 + j] = fmaxf(acc, 0.0f);
    __syncthreads();
    acc = b2[j];
    for (int k = 0; k < HID; k += 4) {
        float4 tv = *(const float4*)&t1s[r * 40 + k];
        acc += tv.x * w2[(k + 0) * HID + j];
        acc += tv.y * w2[(k + 1) * HID + j];
        acc += tv.z * w2[(k + 2) * HID + j];
        acc += tv.w * w2[(k + 3) * HID + j];
    }
    float v = fmaxf(acc, 0.0f) * w3[j];
#pragma unroll
    for (int off = 16; off > 0; off >>= 1) v += __shfl_down(v, off, 32);
    if (j == 0 && node < n) out[node] = v + b3[0];
}

extern "C" void kernel_launch(void* const* d_in, const int* in_sizes, int n_in,
                              void* d_out, int out_size, void* d_ws, size_t ws_size,
                              hipStream_t stream) {
    const float* x     = (const float*)d_in[0];
    const int*   ei    = (const int*)d_in[1];
    const float* W_gcn = (const float*)d_in[2];
    const float* b_gcn = (const float*)d_in[3];
    const float* w1    = (const float*)d_in[4];
    const float* b1    = (const float*)d_in[5];
    const float* w2    = (const float*)d_in[6];
    const float* b2    = (const float*)d_in[7];
    const float* w3    = (const float*)d_in[8];
    const float* b3    = (const float*)d_in[9];
    float* out = (float*)d_out;

    const int n = in_sizes[0] / DIM;     // 50000
    const int E = in_sizes[1] / 2;       // 600000

    // workspace layout
    char* ws = (char*)d_ws;
    unsigned short* xwb = (unsigned short*)ws;              // 12.8 MB bf16
    char* p = ws + (size_t)n * DIM * sizeof(unsigned short);
    int*   degi = (int*)p;           p += (size_t)n * sizeof(int);
    int*   offs = (int*)p;           p += (size_t)n * sizeof(int);
    int*   cur  = (int*)p;           p += (size_t)n * sizeof(int);
    p = (char*)(((size_t)p + 15) & ~(size_t)15);
    int2*  csr  = (int2*)p;                                  // 4.8 MB

    const int nchunk = (n + 1023) / 1024;    // 49
    const int ngemm  = (n + 15) / 16;        // 3125
    const int ndeg   = (E + 1023) / 1024;    // 586

    hipMemsetAsync(degi, 0, (size_t)n * sizeof(int), stream);
    gemm_deg_kernel<<<ngemm + ndeg, 256, 0, stream>>>(x, W_gcn, xwb, ei + E, degi,
                                                      n, E, ngemm);
    scan_kernel<<<nchunk, 256, 0, stream>>>(degi, offs, cur, n);
    fill_kernel<<<(E + 1023) / 1024, 256, 0, stream>>>(ei, degi, cur, csr, E);
    gather_tail_kernel<<<(n + 7) / 8, 256, 0, stream>>>(xwb, x, offs, degi, csr,
                                                        b_gcn, w1, b1, w2, b2,
                                                        w3, b3, out, n);
}

// Round 8
// 220.169 us; speedup vs baseline: 4.8182x; 1.1039x over previous
//
#include <hip/hip_runtime.h>

#define DIM 128
#define HID 32

typedef __attribute__((ext_vector_type(8))) short v8s;
typedef __attribute__((ext_vector_type(4))) float v4f;

// bf16 helpers (RNE), values finite
static __device__ __forceinline__ unsigned short f2bf(float f) {
    unsigned int u = __float_as_uint(f);
    u += 0x7fffu + ((u >> 16) & 1u);
    return (unsigned short)(u >> 16);
}
static __device__ __forceinline__ float bf2f(unsigned short s) {
    return __uint_as_float((unsigned int)s << 16);
}

// ---------------- K1 task list: MFMA gemm tiles (xw bf16) + degree-count chunks ----------------
// gemm block: 64 rows x 128 cols, K=128. 4 waves; wave w owns rows w*16..w*16+15.
// LDS: wt[n][k] (transposed W, bf16, stride 136 = 16B-aligned rows), xs[m][k] same stride.
__global__ __launch_bounds__(256) void gemm_deg_kernel(const float* __restrict__ x,
                                                       const float* __restrict__ W,
                                                       unsigned short* __restrict__ xwb,
                                                       const int* __restrict__ col,
                                                       int* __restrict__ degi,
                                                       int n, int E, int ngemm) {
    __shared__ __attribute__((aligned(16))) unsigned short wt[128 * 136]; // 34.8 KB
    __shared__ __attribute__((aligned(16))) unsigned short xs[64 * 136];  // 17.4 KB
    int t = threadIdx.x;
    if ((int)blockIdx.x < ngemm) {
        int row0 = blockIdx.x * 64;
        // stage W -> wt (transpose + bf16), coalesced float4 reads
#pragma unroll
        for (int i = 0; i < 16; ++i) {
            int f = t + i * 256;           // float4 index over 128x128
            int k  = f >> 5;               // source row of W
            int nc = (f & 31) * 4;         // source cols nc..nc+3
            float4 wv = ((const float4*)W)[f];
            wt[(nc + 0) * 136 + k] = f2bf(wv.x);
            wt[(nc + 1) * 136 + k] = f2bf(wv.y);
            wt[(nc + 2) * 136 + k] = f2bf(wv.z);
            wt[(nc + 3) * 136 + k] = f2bf(wv.w);
        }
        // stage x rows -> xs (bf16)
#pragma unroll
        for (int i = 0; i < 8; ++i) {
            int f = t + i * 256;           // float4 index over 64x128
            int rl = f >> 5;
            int kc = (f & 31) * 4;
            float4 v = make_float4(0.f, 0.f, 0.f, 0.f);
            if (row0 + rl < n) v = ((const float4*)(x + (size_t)(row0 + rl) * DIM))[f & 31];
            xs[rl * 136 + kc + 0] = f2bf(v.x);
            xs[rl * 136 + kc + 1] = f2bf(v.y);
            xs[rl * 136 + kc + 2] = f2bf(v.z);
            xs[rl * 136 + kc + 3] = f2bf(v.w);
        }
        __syncthreads();

        int w = t >> 6;          // wave 0..3
        int l = t & 63;
        int q = l >> 4;          // quad
        int mn = l & 15;
        // A fragments for this wave's 16 rows, all 4 K-steps
        v8s afrag[4];
#pragma unroll
        for (int kt = 0; kt < 4; ++kt)
            afrag[kt] = *(const v8s*)&xs[(w * 16 + mn) * 136 + kt * 32 + q * 8];
        // 8 column tiles of 16
#pragma unroll
        for (int ct = 0; ct < 8; ++ct) {
            v4f acc = {0.f, 0.f, 0.f, 0.f};
#pragma unroll
            for (int kt = 0; kt < 4; ++kt) {
                v8s bfrag = *(const v8s*)&wt[(ct * 16 + mn) * 136 + kt * 32 + q * 8];
                acc = __builtin_amdgcn_mfma_f32_16x16x32_bf16(afrag[kt], bfrag, acc, 0, 0, 0);
            }
            int colg = ct * 16 + mn;
#pragma unroll
            for (int i = 0; i < 4; ++i) {
                int rowg = row0 + w * 16 + q * 4 + i;
                if (rowg < n) xwb[(size_t)rowg * DIM + colg] = f2bf(acc[i]);
            }
        }
    } else {
        int base = ((blockIdx.x - ngemm) * 256 + t) * 4;
        if (base + 3 < E) {
            int4 v = *(const int4*)&col[base];
            atomicAdd(&degi[v.x], 1); atomicAdd(&degi[v.y], 1);
            atomicAdd(&degi[v.z], 1); atomicAdd(&degi[v.w], 1);
        } else {
            for (int e = base; e < E; ++e) atomicAdd(&degi[col[e]], 1);
        }
    }
}

// ---------------- single-dispatch scan: offs/cur = exclusive_scan(degi) ----------------
__global__ __launch_bounds__(256) void scan_kernel(const int* __restrict__ degi,
                                                   int* __restrict__ offs,
                                                   int* __restrict__ cur, int n) {
    __shared__ int sh[16];
    const int c = blockIdx.x, t = threadIdx.x;
    const int lim = c << 10;
    int s = 0;
    for (int i = t * 4; i < lim; i += 1024) {
        int4 q = *(const int4*)&degi[i];
        s += q.x + q.y + q.z + q.w;
    }
#pragma unroll
    for (int off = 32; off > 0; off >>= 1) s += __shfl_down(s, off);
    if ((t & 63) == 0) sh[t >> 6] = s;
    __syncthreads();
    if (t == 0) sh[4] = sh[0] + sh[1] + sh[2] + sh[3];
    __syncthreads();
    const int pre = sh[4];

    int i0 = lim + t * 4;
    int va = 0, vb = 0, vc = 0, vd = 0;
    if (i0 + 3 < n) {
        int4 q = *(const int4*)&degi[i0];
        va = q.x; vb = q.y; vc = q.z; vd = q.w;
    } else {
        if (i0     < n) va = degi[i0];
        if (i0 + 1 < n) vb = degi[i0 + 1];
        if (i0 + 2 < n) vc = degi[i0 + 2];
    }
    int s1 = va + vb, s2 = s1 + vc, tot = s2 + vd;
    int lane = t & 63;
    int inc = tot;
#pragma unroll
    for (int off = 1; off < 64; off <<= 1) {
        int u = __shfl_up(inc, off);
        if (lane >= off) inc += u;
    }
    int texcl = inc - tot;
    if (lane == 63) sh[8 + (t >> 6)] = inc;
    __syncthreads();
    if (t == 0) {
        int a = 0;
#pragma unroll
        for (int w = 0; w < 4; ++w) { int u = sh[8 + w]; sh[12 + w] = a; a += u; }
    }
    __syncthreads();
    int excl = pre + sh[12 + (t >> 6)] + texcl;
    if (i0 + 3 < n) {
        int4 o; o.x = excl; o.y = excl + va; o.z = excl + s1; o.w = excl + s2;
        *(int4*)&offs[i0] = o;
        *(int4*)&cur[i0]  = o;
    } else {
        if (i0     < n) { offs[i0]     = excl;      cur[i0]     = excl; }
        if (i0 + 1 < n) { offs[i0 + 1] = excl + va; cur[i0 + 1] = excl + va; }
        if (i0 + 2 < n) { offs[i0 + 2] = excl + s1; cur[i0 + 2] = excl + s1; }
    }
}

// ---------------- fill CSR buckets, 4 edges/thread ----------------
__global__ __launch_bounds__(256) void fill_kernel(const int* __restrict__ ei,
                                                   const int* __restrict__ degi,
                                                   int* __restrict__ cur,
                                                   int2* __restrict__ csr, int E) {
    const int* col = ei + E;
    int base = (blockIdx.x * 256 + threadIdx.x) * 4;
    if (base + 3 < E) {
        int4 r4 = *(const int4*)&ei[base];
        int4 c4 = *(const int4*)&col[base];
        int p0 = atomicAdd(&cur[c4.x], 1);
        int p1 = atomicAdd(&cur[c4.y], 1);
        int p2 = atomicAdd(&cur[c4.z], 1);
        int p3 = atomicAdd(&cur[c4.w], 1);
        csr[p0] = make_int2(r4.x, __float_as_int(rsqrtf((float)degi[r4.x] + 1.0f)));
        csr[p1] = make_int2(r4.y, __float_as_int(rsqrtf((float)degi[r4.y] + 1.0f)));
        csr[p2] = make_int2(r4.z, __float_as_int(rsqrtf((float)degi[r4.z] + 1.0f)));
        csr[p3] = make_int2(r4.w, __float_as_int(rsqrtf((float)degi[r4.w] + 1.0f)));
    } else {
        for (int e = base; e < E; ++e) {
            int r = ei[e], c = col[e];
            int p = atomicAdd(&cur[c], 1);
            csr[p] = make_int2(r, __float_as_int(rsqrtf((float)degi[r] + 1.0f)));
        }
    }
}

// ---------------- fused: CSR gather + self-loop + bias/relu/residual + MLP ----------------
// 8 nodes/block; 32 threads/node; thread j owns channels 4j..4j+3. Edge loop 8x unrolled.
__global__ __launch_bounds__(256) void gather_tail_kernel(
    const unsigned short* __restrict__ xwb, const float* __restrict__ x,
    const int* __restrict__ offs, const int* __restrict__ degi,
    const int2* __restrict__ csr, const float* __restrict__ b_gcn,
    const float* __restrict__ w1, const float* __restrict__ b1,
    const float* __restrict__ w2, const float* __restrict__ b2,
    const float* __restrict__ w3, const float* __restrict__ b3,
    float* __restrict__ out, int n) {
    __shared__ float hs[8 * 132];
    __shared__ float t1s[8 * 40];
    int t = threadIdx.x;
    int r = t >> 5, j = t & 31;
    int node = blockIdx.x * 8 + r;

    if (node < n) {
        int beg = offs[node];
        int d = degi[node];
        // prefetch node-own data before the edge loop
        ushort4 a = ((const ushort4*)(xwb + (size_t)node * DIM))[j];
        float4 xv = ((const float4*)(x + (size_t)node * DIM))[j];
        float4 bg = ((const float4*)b_gcn)[j];
        float ax = 0.f, ay = 0.f, az = 0.f, aw = 0.f;
        for (int c0 = 0; c0 < d; c0 += 32) {
            int2 e = make_int2(0, 0);
            if (c0 + j < d) e = csr[beg + c0 + j];
            int m = min(32, d - c0);
            int i = 0;
            for (; i + 8 <= m; i += 8) {
                ushort4 v[8]; float wgt[8];
#pragma unroll
                for (int u = 0; u < 8; ++u) {
                    int src = __shfl(e.x, i + u, 32);
                    wgt[u] = __int_as_float(__shfl(e.y, i + u, 32));
                    v[u] = ((const ushort4*)(xwb + (size_t)src * DIM))[j];
                }
#pragma unroll
                for (int u = 0; u < 8; ++u) {
                    ax += wgt[u] * bf2f(v[u].x); ay += wgt[u] * bf2f(v[u].y);
                    az += wgt[u] * bf2f(v[u].z); aw += wgt[u] * bf2f(v[u].w);
                }
            }
            for (; i + 4 <= m; i += 4) {
                ushort4 v[4]; float wgt[4];
#pragma unroll
                for (int u = 0; u < 4; ++u) {
                    int src = __shfl(e.x, i + u, 32);
                    wgt[u] = __int_as_float(__shfl(e.y, i + u, 32));
                    v[u] = ((const ushort4*)(xwb + (size_t)src * DIM))[j];
                }
#pragma unroll
                for (int u = 0; u < 4; ++u) {
                    ax += wgt[u] * bf2f(v[u].x); ay += wgt[u] * bf2f(v[u].y);
                    az += wgt[u] * bf2f(v[u].z); aw += wgt[u] * bf2f(v[u].w);
                }
            }
            for (; i < m; ++i) {
                int src = __shfl(e.x, i, 32);
                float w = __int_as_float(__shfl(e.y, i, 32));
                ushort4 v0 = ((const ushort4*)(xwb + (size_t)src * DIM))[j];
                ax += w * bf2f(v0.x); ay += w * bf2f(v0.y);
                az += w * bf2f(v0.z); aw += w * bf2f(v0.w);
            }
        }
        float di = rsqrtf((float)d + 1.0f);
        float sdi = di * di;
        float* h = &hs[r * 132 + 4 * j];
        h[0] = fmaxf(di * ax + sdi * bf2f(a.x) + bg.x, 0.f) + xv.x;
        h[1] = fmaxf(di * ay + sdi * bf2f(a.y) + bg.y, 0.f) + xv.y;
        h[2] = fmaxf(di * az + sdi * bf2f(a.z) + bg.z, 0.f) + xv.z;
        h[3] = fmaxf(di * aw + sdi * bf2f(a.w) + bg.w, 0.f) + xv.w;
    }
    __syncthreads();
    float acc = b1[j];
    for (int k = 0; k < DIM; k += 4) {
        float4 hv = *(const float4*)&hs[r * 132 + k];
        acc += hv.x * w1[(k + 0) * HID + j];
        acc += hv.y * w1[(k + 1) * HID + j];
        acc += hv.z * w1[(k + 2) * HID + j];
        acc += hv.w * w1[(k + 3) * HID + j];
    }
    t1s[r * 40 + j] = fmaxf(acc, 0.0f);
    __syncthreads();
    acc = b2[j];
    for (int k = 0; k < HID; k += 4) {
        float4 tv = *(const float4*)&t1s[r * 40 + k];
        acc += tv.x * w2[(k + 0) * HID + j];
        acc += tv.y * w2[(k + 1) * HID + j];
        acc += tv.z * w2[(k + 2) * HID + j];
        acc += tv.w * w2[(k + 3) * HID + j];
    }
    float v = fmaxf(acc, 0.0f) * w3[j];
#pragma unroll
    for (int off = 16; off > 0; off >>= 1) v += __shfl_down(v, off, 32);
    if (j == 0 && node < n) out[node] = v + b3[0];
}

extern "C" void kernel_launch(void* const* d_in, const int* in_sizes, int n_in,
                              void* d_out, int out_size, void* d_ws, size_t ws_size,
                              hipStream_t stream) {
    const float* x     = (const float*)d_in[0];
    const int*   ei    = (const int*)d_in[1];
    const float* W_gcn = (const float*)d_in[2];
    const float* b_gcn = (const float*)d_in[3];
    const float* w1    = (const float*)d_in[4];
    const float* b1    = (const float*)d_in[5];
    const float* w2    = (const float*)d_in[6];
    const float* b2    = (const float*)d_in[7];
    const float* w3    = (const float*)d_in[8];
    const float* b3    = (const float*)d_in[9];
    float* out = (float*)d_out;

    const int n = in_sizes[0] / DIM;     // 50000
    const int E = in_sizes[1] / 2;       // 600000

    // workspace layout
    char* ws = (char*)d_ws;
    unsigned short* xwb = (unsigned short*)ws;              // 12.8 MB bf16
    char* p = ws + (size_t)n * DIM * sizeof(unsigned short);
    int*   degi = (int*)p;           p += (size_t)n * sizeof(int);
    int*   offs = (int*)p;           p += (size_t)n * sizeof(int);
    int*   cur  = (int*)p;           p += (size_t)n * sizeof(int);
    p = (char*)(((size_t)p + 15) & ~(size_t)15);
    int2*  csr  = (int2*)p;                                  // 4.8 MB

    const int nchunk = (n + 1023) / 1024;    // 49
    const int ngemm  = (n + 63) / 64;        // 782
    const int ndeg   = (E + 1023) / 1024;    // 586

    hipMemsetAsync(degi, 0, (size_t)n * sizeof(int), stream);
    gemm_deg_kernel<<<ngemm + ndeg, 256, 0, stream>>>(x, W_gcn, xwb, ei + E, degi,
                                                      n, E, ngemm);
    scan_kernel<<<nchunk, 256, 0, stream>>>(degi, offs, cur, n);
    fill_kernel<<<(E + 1023) / 1024, 256, 0, stream>>>(ei, degi, cur, csr, E);
    gather_tail_kernel<<<(n + 7) / 8, 256, 0, stream>>>(xwb, x, offs, degi, csr,
                                                        b_gcn, w1, b1, w2, b2,
                                                        w3, b3, out, n);
}